// Round 9
// baseline (64.307 us; speedup 1.0000x reference)
//
#include <hip/hip_runtime.h>
#include <stdint.h>

// DCN forward: B=4, H=128, W=128, G=8, C=32, K=8
// inputs      [B,H,W,G,C]   fp32
// deformables [B,H,W,G,K,2] fp32
// weights     [B,H,W,G,K]   fp32
// out         [B,H,W,G,C]   fp32
//
// R9: cooperative parameter pass.
//  Phase A: 512 threads == 64 pixels x 8 k -> each thread does the coordinate/
//    clamp/weight math for ONE (pixel,k) pair and writes float4 weights +
//    int4 offsets to LDS params. Kills the 8x duplication of coord math
//    across the c4 lanes (R8 was VALU-bound at 80% busy).
//  Phase B: per k: 2 broadcast ds_read_b128 (params) + 4 conflict-free tile
//    gathers + 16 v_fmac. Offsets with bit30 set = rare out-of-halo sample
//    (P~0.5%) -> direct global gather (identical reference semantics).
//  Halo RH=3: 14x14 cells, plane pitch 197 (odd -> 8-lane phases hit 8
//    distinct bank groups). Tile 25.2 KB + params 16.4 KB -> 3 blocks/CU.

#define Bc 4
#define Hc 128
#define Wc 128
#define Gc 8
#define Cc 32
#define Kc 8
#define TH 8
#define TW 8
#define RH 3
#define WN 14            // 14x14 cell window
#define NCELL (WN*WN)    // 196
#define PITCH 197        // odd plane pitch (float4 units)
#define FLAGB (1 << 30)

typedef float float4v __attribute__((ext_vector_type(4)));
typedef float float2v __attribute__((ext_vector_type(2)));
typedef int   int4v   __attribute__((ext_vector_type(4)));

__global__ __launch_bounds__(512, 6) void dcn_fwd(
    const float* __restrict__ inp,
    const float* __restrict__ def,
    const float* __restrict__ wts,
    float* __restrict__ out)
{
    const int tid = threadIdx.x;
    const int c4  = tid & 7;      // slot: 4 channels
    const int px  = tid >> 3;     // 0..63 pixel in tile

    // grid: wt(16), ht(16), g(8), b(4)
    const int blk = blockIdx.x;
    const int wt = blk & 15;
    const int ht = (blk >> 4) & 15;
    const int g  = (blk >> 8) & 7;
    const int b  = blk >> 11;

    const int h0 = ht * TH, w0 = wt * TW;
    const int row0 = h0 - RH, col0 = w0 - RH;   // window origin (may be <0)

    // global plane as float4 units: index = y*8192 + x*64 + u
    const float4v* gp4 = (const float4v*)((const char*)inp
        + ((size_t)b << 24) + ((size_t)g << 7));

    __shared__ float4v tile[8 * PITCH];   // 25216 B
    __shared__ float4v pwts[64 * 8];      //  8192 B
    __shared__ int4v   poff[64 * 8];      //  8192 B

    // ---- stage 14x14 cell window into [slot][PITCH] layout ----
#pragma unroll
    for (int r = 0; r < 4; ++r) {
        const int idx = r * 512 + tid;          // 1568 float4 total
        if (idx < NCELL * 8) {
            const int cell = idx >> 3;
            const int u    = idx & 7;
            const int rr   = cell / WN;
            const int cc   = cell - rr * WN;
            const int gr   = min(max(row0 + rr, 0), Hc - 1);
            const int gc   = min(max(col0 + cc, 0), Wc - 1);
            tile[u * PITCH + cell] = gp4[gr * 8192 + gc * 64 + u];
        }
    }

    // ---- Phase A: this thread owns (pixel pxA = px, k = c4) ----
    {
        const int kA = c4;
        const int hA = h0 + (px >> 3);
        const int wA = w0 + (px & 7);
        const int pgA = ((b * Hc + hA) * Wc + wA) * Gc + g;

        const float2v dA = *(const float2v*)(def + (size_t)pgA * 16 + kA * 2);
        const float wk   = wts[(size_t)pgA * 8 + kA];
        const float dx = dA.x, dy = dA.y;

        const float x = dx + (float)wA;
        const float y = dy + (float)hA;

        // truncation toward zero, matching .astype(int32)
        const int fx = (int)x;
        const int fy = (int)y;

        const float wx1 = x - (float)fx;       // exact
        const float wy1 = y - (float)fy;
        const float wx0 = 1.0f - wx1;          // == cxf - x
        const float wy0 = 1.0f - wy1;

        const float ax0 = ((uint32_t)fx       < (uint32_t)Wc) ? wx0 : 0.f;
        const float ax1 = ((uint32_t)(fx + 1) < (uint32_t)Wc) ? wx1 : 0.f;
        const float ay0 = ((uint32_t)fy       < (uint32_t)Hc) ? wy0 : 0.f;
        const float ay1 = ((uint32_t)(fy + 1) < (uint32_t)Hc) ? wy1 : 0.f;

        // TRUE reference clamps
        const int xf = min(max(fx,     0), Wc - 1);
        const int xc = min(max(fx + 1, 0), Wc - 1);
        const int yf = min(max(fy,     0), Hc - 1);
        const int yc = min(max(fy + 1, 0), Hc - 1);

        const float ay0k = wk * ay0;
        const float ay1k = wk * ay1;
        float4v cw;
        cw.x = ay0k * ax0;
        cw.y = ay0k * ax1;
        cw.z = ay1k * ax0;
        cw.w = ay1k * ax1;

        int4v ov;
        const bool inh = (fabsf(dx) < (float)RH) & (fabsf(dy) < (float)RH);
        if (__builtin_expect(inh, 1)) {
            // containment proven (incl. edge clamps): indices in [0, NCELL)
            const int ry0 = yf - row0, ry1 = yc - row0;
            const int rx0 = xf - col0, rx1 = xc - col0;
            const int yA = ry0 * WN, yB = ry1 * WN;
            ov.x = yA + rx0;
            ov.y = yA + rx1;
            ov.z = yB + rx0;
            ov.w = yB + rx1;
        } else {
            // global float4-unit offsets (sans c4), flagged via bit30
            ov.x = ((yf << 13) + (xf << 6)) | FLAGB;
            ov.y = ((yf << 13) + (xc << 6)) | FLAGB;
            ov.z = ((yc << 13) + (xf << 6)) | FLAGB;
            ov.w = ((yc << 13) + (xc << 6)) | FLAGB;
        }
        pwts[px * 8 + kA] = cw;
        poff[px * 8 + kA] = ov;
    }
    __syncthreads();

    // ---- Phase B: gather + FMA ----
    const int pb = px * 8;
    const int cb = c4 * PITCH;

    float4v acc0 = {0.f, 0.f, 0.f, 0.f};
    float4v acc1 = {0.f, 0.f, 0.f, 0.f};

#pragma unroll
    for (int k = 0; k < Kc; ++k) {
        const float4v cw = pwts[pb + k];
        const int4v  ov = poff[pb + k];
        if (__builtin_expect(ov.x < FLAGB, 1)) {
            acc0 += cw.x * tile[cb + ov.x];
            acc1 += cw.y * tile[cb + ov.y];
            acc0 += cw.z * tile[cb + ov.z];
            acc1 += cw.w * tile[cb + ov.w];
        } else {
            const int m = FLAGB - 1;
            acc0 += cw.x * gp4[(ov.x & m) + c4];
            acc1 += cw.y * gp4[(ov.y & m) + c4];
            acc0 += cw.z * gp4[(ov.z & m) + c4];
            acc1 += cw.w * gp4[(ov.w & m) + c4];
        }
    }

    const int h = h0 + (px >> 3);
    const int w = w0 + (px & 7);
    const int pg = ((b * Hc + h) * Wc + w) * Gc + g;
    const float4v acc = acc0 + acc1;
    ((float4v*)((char*)out + (size_t)pg * 128))[c4] = acc;
}

extern "C" void kernel_launch(void* const* d_in, const int* in_sizes, int n_in,
                              void* d_out, int out_size, void* d_ws, size_t ws_size,
                              hipStream_t stream) {
    const float* inp = (const float*)d_in[0];
    const float* def = (const float*)d_in[1];
    const float* wts = (const float*)d_in[2];
    float* out = (float*)d_out;

    const int nblocks = Bc * Gc * (Hc / TH) * (Wc / TW);  // 8192
    dcn_fwd<<<nblocks, 512, 0, stream>>>(inp, def, wts, out);
}